// Round 2
// baseline (648.638 us; speedup 1.0000x reference)
//
#include <hip/hip_runtime.h>

constexpr int N = 50000;
constexpr int E = 400000;
constexpr int D = 100;
constexpr int B = 4;
constexpr float NEG_SLOPE = 0.2f;

constexpr int SCAN_CHUNK = 2048;
constexpr int NB_SCAN = (N + SCAN_CHUNK - 1) / SCAN_CHUNK;  // 25
constexpr int CAP = 128;  // per-node LDS edge cache; deg>CAP falls back (Poisson(8): never)

// ---------------- CSR build (counting sort of edges by dst) ----------------

__global__ void k_hist(const int* __restrict__ dst, int* __restrict__ deg) {
  int i = blockIdx.x * blockDim.x + threadIdx.x;
  int stride = gridDim.x * blockDim.x;
  for (; i < E; i += stride) atomicAdd(&deg[dst[i]], 1);
}

__global__ void k_scan1(const int* __restrict__ deg, int* __restrict__ incl,
                        int* __restrict__ bsums) {
  __shared__ int lds[256];
  int tid = threadIdx.x;
  int base = blockIdx.x * SCAN_CHUNK + tid * 8;
  int v[8]; int s = 0;
#pragma unroll
  for (int j = 0; j < 8; ++j) {
    int idx = base + j;
    int x = (idx < N) ? deg[idx] : 0;
    v[j] = x; s += x;
  }
  lds[tid] = s; __syncthreads();
  for (int off = 1; off < 256; off <<= 1) {
    int t = (tid >= off) ? lds[tid - off] : 0;
    __syncthreads();
    lds[tid] += t;
    __syncthreads();
  }
  int run = lds[tid] - s;  // exclusive prefix within block
#pragma unroll
  for (int j = 0; j < 8; ++j) {
    int idx = base + j;
    run += v[j];
    if (idx < N) incl[idx] = run;  // inclusive scan within block
  }
  if (tid == 255) bsums[blockIdx.x] = lds[255];
}

__global__ void k_scan2(int* __restrict__ bsums, int nb) {
  if (threadIdx.x == 0 && blockIdx.x == 0) {
    int run = 0;
    for (int i = 0; i < nb; ++i) { int t = bsums[i]; bsums[i] = run; run += t; }
  }
}

__global__ void k_scan3(const int* __restrict__ incl, const int* __restrict__ bsums,
                        int* __restrict__ offs) {
  int i = blockIdx.x * blockDim.x + threadIdx.x;
  int stride = gridDim.x * blockDim.x;
  for (; i < N; i += stride) {
    offs[i + 1] = incl[i] + bsums[i / SCAN_CHUNK];
    if (i == 0) offs[0] = 0;
  }
}

// scatter edges into CSR order; also permute src/etype into position order so
// downstream kernels read contiguous ranges (no indirect per-edge gathers).
__global__ void k_scatter(const int* __restrict__ srcArr, const int* __restrict__ dst,
                          const int* __restrict__ etype, const int* __restrict__ offs,
                          int* __restrict__ cursor, int* __restrict__ ssorted,
                          int* __restrict__ esorted) {
  int i = blockIdx.x * blockDim.x + threadIdx.x;
  int stride = gridDim.x * blockDim.x;
  for (; i < E; i += stride) {
    int d = dst[i];
    int pos = offs[d] + atomicAdd(&cursor[d], 1);
    ssorted[pos] = srcArr[i];
    esorted[pos] = etype[i];
  }
}

// ---------------- per-layer kernels ----------------

// qb[b,i] = sum_o basis[b,i,o] * q[o];  kb likewise.
__global__ void k_qbkb(const float* __restrict__ basis, const float* __restrict__ qv,
                       const float* __restrict__ kv, float* __restrict__ qb,
                       float* __restrict__ kb) {
  int t = blockIdx.x * blockDim.x + threadIdx.x;
  if (t < B * D) {
    const float* row = basis + t * D;  // t = b*D+i -> row (b,i,:)
    float sq = 0.f, sk = 0.f;
    for (int o = 0; o < D; ++o) { float r = row[o]; sq += r * qv[o]; sk += r * kv[o]; }
    qb[t] = sq; kb[t] = sk;
  }
}

// xq[n,b] = x[n,:].qb[b,:] ; xk[n,b] = x[n,:].kb[b,:]   (one wave per node)
__global__ __launch_bounds__(64) void k_xqxk(
    const float* __restrict__ feat, const int* __restrict__ remap,
    const float* __restrict__ qb, const float* __restrict__ kb,
    float* __restrict__ xq, float* __restrict__ xk) {
  int n = blockIdx.x;
  int lane = threadIdx.x;
  int row = remap ? remap[n] : n;
  const float* x = feat + (long)row * D;
  float v0 = x[lane];
  bool hi = (lane < D - 64);
  float v1 = hi ? x[64 + lane] : 0.f;
#pragma unroll
  for (int b = 0; b < B; ++b) {
    float wq1 = hi ? qb[b * D + 64 + lane] : 0.f;
    float wk1 = hi ? kb[b * D + 64 + lane] : 0.f;
    float pq = v0 * qb[b * D + lane] + v1 * wq1;
    float pk = v0 * kb[b * D + lane] + v1 * wk1;
#pragma unroll
    for (int off = 32; off >= 1; off >>= 1) {
      pq += __shfl_xor(pq, off);
      pk += __shfl_xor(pk, off);
    }
    if (lane == 0) { xq[n * B + b] = pq; xk[n * B + b] = pk; }
  }
}

__device__ __forceinline__ float edge_score_p(int s, int et,
                                              const float* __restrict__ att,
                                              const float4 xq4,
                                              const float* __restrict__ xk,
                                              float4* a_out) {
  float4 a = *(const float4*)(att + et * 4);
  float4 xs = *(const float4*)(xk + s * 4);
  float qe = a.x * xq4.x + a.y * xq4.y + a.z * xq4.z + a.w * xq4.w;
  float ke = a.x * xs.x + a.y * xs.y + a.z * xs.z + a.w * xs.w;
  float sc = qe + ke;
  *a_out = a;
  return sc >= 0.f ? sc : NEG_SLOPE * sc;
}

// One block (128 thr) per dst node: softmax over its edges + input-space aggregation.
// agg[n,b,:] = sum_edges alpha_e * att[et,b] * x[src,:]
__global__ __launch_bounds__(128) void k_node(
    const float* __restrict__ feat, const int* __restrict__ remap,
    const int* __restrict__ ssorted, const int* __restrict__ esorted,
    const float* __restrict__ att, const float* __restrict__ xq,
    const float* __restrict__ xk, const int* __restrict__ offs,
    float* __restrict__ agg) {
  int n = blockIdx.x;
  int tid = threadIdx.x;
  int lane = tid & 63, wid = tid >> 6;
  int o0 = offs[n], o1 = offs[n + 1];
  int deg = o1 - o0;
  float4 xq4 = *(const float4*)(xq + n * 4);
  __shared__ float red[2];
  __shared__ float sc[CAP];
  __shared__ float4 a4[CAP];
  __shared__ int sbuf[CAP];

  if (deg <= CAP) {
    // compute each edge score ONCE; cache score, att-row, src in LDS
    for (int i = tid; i < deg; i += 128) {
      int s = ssorted[o0 + i];
      int et = esorted[o0 + i];
      float4 a;
      float v = edge_score_p(s, et, att, xq4, xk, &a);
      sc[i] = v; a4[i] = a; sbuf[i] = s;
    }
    __syncthreads();
    // segment max
    float lm = -3.4e38f;
    for (int i = tid; i < deg; i += 128) lm = fmaxf(lm, sc[i]);
#pragma unroll
    for (int off = 32; off >= 1; off >>= 1) lm = fmaxf(lm, __shfl_xor(lm, off));
    if (lane == 0) red[wid] = lm;
    __syncthreads();
    float m = fmaxf(red[0], red[1]);
    __syncthreads();
    // segment sum of exp (stash exp back into sc)
    float ls = 0.f;
    for (int i = tid; i < deg; i += 128) {
      float ex = __expf(sc[i] - m);
      sc[i] = ex;
      ls += ex;
    }
#pragma unroll
    for (int off = 32; off >= 1; off >>= 1) ls += __shfl_xor(ls, off);
    if (lane == 0) red[wid] = ls;
    __syncthreads();
    float inv = 1.f / (red[0] + red[1] + 1e-16f);
    // fold alpha into the att row (each thread owns its own i's — no race)
    for (int i = tid; i < deg; i += 128) {
      float p = sc[i] * inv;
      float4 a = a4[i];
      a.x *= p; a.y *= p; a.z *= p; a.w *= p;
      a4[i] = a;
    }
    __syncthreads();
    // aggregate x[src] with per-basis coefficients (threads = feature dim)
    if (tid < D) {
      float acc0 = 0.f, acc1 = 0.f, acc2 = 0.f, acc3 = 0.f;
      for (int i = 0; i < deg; ++i) {
        float4 a = a4[i];
        int s = sbuf[i];
        int rrow = remap ? remap[s] : s;
        float xv = feat[(long)rrow * D + tid];
        acc0 += a.x * xv;
        acc1 += a.y * xv;
        acc2 += a.z * xv;
        acc3 += a.w * xv;
      }
      float* ag = agg + (long)n * (B * D) + tid;
      ag[0 * D] = acc0; ag[1 * D] = acc1; ag[2 * D] = acc2; ag[3 * D] = acc3;
    }
  } else {
    // fallback: recompute path (correct for any deg)
    float lm = -3.4e38f;
    for (int i = tid; i < deg; i += 128) {
      float4 a;
      lm = fmaxf(lm, edge_score_p(ssorted[o0 + i], esorted[o0 + i], att, xq4, xk, &a));
    }
#pragma unroll
    for (int off = 32; off >= 1; off >>= 1) lm = fmaxf(lm, __shfl_xor(lm, off));
    if (lane == 0) red[wid] = lm;
    __syncthreads();
    float m = fmaxf(red[0], red[1]);
    __syncthreads();
    float ls = 0.f;
    for (int i = tid; i < deg; i += 128) {
      float4 a;
      ls += __expf(edge_score_p(ssorted[o0 + i], esorted[o0 + i], att, xq4, xk, &a) - m);
    }
#pragma unroll
    for (int off = 32; off >= 1; off >>= 1) ls += __shfl_xor(ls, off);
    if (lane == 0) red[wid] = ls;
    __syncthreads();
    float inv = 1.f / (red[0] + red[1] + 1e-16f);
    if (tid < D) {
      float acc0 = 0.f, acc1 = 0.f, acc2 = 0.f, acc3 = 0.f;
      for (int i = 0; i < deg; ++i) {
        int s = ssorted[o0 + i];
        float4 a;
        float v = edge_score_p(s, esorted[o0 + i], att, xq4, xk, &a);
        float p = __expf(v - m) * inv;
        int rrow = remap ? remap[s] : s;
        float xv = feat[(long)rrow * D + tid];
        acc0 += p * a.x * xv;
        acc1 += p * a.y * xv;
        acc2 += p * a.z * xv;
        acc3 += p * a.w * xv;
      }
      float* ag = agg + (long)n * (B * D) + tid;
      ag[0 * D] = acc0; ag[1 * D] = acc1; ag[2 * D] = acc2; ag[3 * D] = acc3;
    }
  }
}

// out[n,o] = sum_k agg[n,k] * W[k,o] + bias[o]   (W = basis viewed [400,100]), opt ReLU
template <bool RELU>
__global__ __launch_bounds__(256) void k_gemm(const float* __restrict__ A,
                                              const float* __restrict__ W,
                                              const float* __restrict__ bias,
                                              float* __restrict__ out) {
  __shared__ float A_lds[32][33];   // [k][node]
  __shared__ float W_lds[32][128];  // [k][o], o padded to 128 with zeros
  int tid = threadIdx.x;
  int nblk = blockIdx.x * 32;
  int o_base = (tid & 31) * 4;
  int n_base = (tid >> 5) * 4;
  float acc[4][4] = {};
  int anode = tid >> 3;
  int ak = (tid & 7) * 4;
  for (int kc = 0; kc < 400; kc += 32) {
    float4 av = make_float4(0.f, 0.f, 0.f, 0.f);
    int gn = nblk + anode;
    if (gn < N && kc + ak < 400) av = *(const float4*)(A + (long)gn * 400 + kc + ak);
    A_lds[ak + 0][anode] = av.x;
    A_lds[ak + 1][anode] = av.y;
    A_lds[ak + 2][anode] = av.z;
    A_lds[ak + 3][anode] = av.w;
    for (int li = tid; li < 32 * 128; li += 256) {
      int k = li >> 7, o = li & 127;
      float v = 0.f;
      if (o < D && kc + k < 400) v = W[(kc + k) * D + o];
      W_lds[k][o] = v;
    }
    __syncthreads();
#pragma unroll
    for (int k = 0; k < 32; ++k) {
      float4 w = *(const float4*)&W_lds[k][o_base];
      float a0 = A_lds[k][n_base + 0];
      float a1 = A_lds[k][n_base + 1];
      float a2 = A_lds[k][n_base + 2];
      float a3 = A_lds[k][n_base + 3];
      acc[0][0] += a0 * w.x; acc[0][1] += a0 * w.y; acc[0][2] += a0 * w.z; acc[0][3] += a0 * w.w;
      acc[1][0] += a1 * w.x; acc[1][1] += a1 * w.y; acc[1][2] += a1 * w.z; acc[1][3] += a1 * w.w;
      acc[2][0] += a2 * w.x; acc[2][1] += a2 * w.y; acc[2][2] += a2 * w.z; acc[2][3] += a2 * w.w;
      acc[3][0] += a3 * w.x; acc[3][1] += a3 * w.y; acc[3][2] += a3 * w.z; acc[3][3] += a3 * w.w;
    }
    __syncthreads();
  }
  if (o_base < D) {
    float4 bv = *(const float4*)(bias + o_base);
#pragma unroll
    for (int j = 0; j < 4; ++j) {
      int n = nblk + n_base + j;
      if (n < N) {
        float4 r;
        r.x = acc[j][0] + bv.x; r.y = acc[j][1] + bv.y;
        r.z = acc[j][2] + bv.z; r.w = acc[j][3] + bv.w;
        if (RELU) {
          r.x = fmaxf(r.x, 0.f); r.y = fmaxf(r.y, 0.f);
          r.z = fmaxf(r.z, 0.f); r.w = fmaxf(r.w, 0.f);
        }
        *(float4*)(out + (long)n * D + o_base) = r;
      }
    }
  }
}

// ---------------- launch ----------------

extern "C" void kernel_launch(void* const* d_in, const int* in_sizes, int n_in,
                              void* d_out, int out_size, void* d_ws, size_t ws_size,
                              hipStream_t stream) {
  const int* entity = (const int*)d_in[0];
  const int* edge_index = (const int*)d_in[1];
  const int* etype = (const int*)d_in[2];
  // d_in[3] = edge_norm: unused by the reference
  const float* emb = (const float*)d_in[4];
  const float* basis1 = (const float*)d_in[5];
  const float* att1 = (const float*)d_in[6];
  const float* q1 = (const float*)d_in[7];
  const float* k1 = (const float*)d_in[8];
  const float* bias1 = (const float*)d_in[9];
  const float* basis2 = (const float*)d_in[10];
  const float* att2 = (const float*)d_in[11];
  const float* q2 = (const float*)d_in[12];
  const float* k2 = (const float*)d_in[13];
  const float* bias2 = (const float*)d_in[14];
  float* out = (float*)d_out;

  const int* srcArr = edge_index;       // edge_index[0,:]
  const int* dstArr = edge_index + E;   // edge_index[1,:]

  // workspace layout (~88 MB)
  float* ws = (float*)d_ws;
  float* agg = ws;                               // N*B*D = 20,000,000 floats
  float* xq = agg + (size_t)N * B * D;           // N*B
  float* xk = xq + (size_t)N * B;                // N*B
  float* qb = xk + (size_t)N * B;                // B*D
  float* kb = qb + B * D;                        // B*D
  int* ssorted = (int*)(kb + B * D);             // E
  int* esorted = ssorted + E;                    // E
  int* offs = esorted + E;                       // N+1
  int* deg = offs + (N + 1);                     // N
  int* cursor = deg + N;                         // N
  int* incl = cursor + N;                        // N
  int* bsums = incl + N;                         // NB_SCAN

  hipMemsetAsync(deg, 0, N * sizeof(int), stream);
  hipMemsetAsync(cursor, 0, N * sizeof(int), stream);
  k_hist<<<512, 256, 0, stream>>>(dstArr, deg);
  k_scan1<<<NB_SCAN, 256, 0, stream>>>(deg, incl, bsums);
  k_scan2<<<1, 64, 0, stream>>>(bsums, NB_SCAN);
  k_scan3<<<256, 256, 0, stream>>>(incl, bsums, offs);
  k_scatter<<<512, 256, 0, stream>>>(srcArr, dstArr, etype, offs, cursor, ssorted, esorted);

  // ---- layer 1: x = emb[entity] (via remap), ReLU; x1 stored in d_out ----
  k_qbkb<<<2, 256, 0, stream>>>(basis1, q1, k1, qb, kb);
  k_xqxk<<<N, 64, 0, stream>>>(emb, entity, qb, kb, xq, xk);
  k_node<<<N, 128, 0, stream>>>(emb, entity, ssorted, esorted, att1, xq, xk, offs, agg);
  k_gemm<true><<<(N + 31) / 32, 256, 0, stream>>>(agg, basis1, bias1, out);

  // ---- layer 2: x = x1 (in d_out), no ReLU ----
  k_qbkb<<<2, 256, 0, stream>>>(basis2, q2, k2, qb, kb);
  k_xqxk<<<N, 64, 0, stream>>>(out, nullptr, qb, kb, xq, xk);
  k_node<<<N, 128, 0, stream>>>(out, nullptr, ssorted, esorted, att2, xq, xk, offs, agg);
  k_gemm<false><<<(N + 31) / 32, 256, 0, stream>>>(agg, basis2, bias2, out);
}

// Round 4
// 506.650 us; speedup vs baseline: 1.2802x; 1.2802x over previous
//
#include <hip/hip_runtime.h>

constexpr int N = 50000;
constexpr int E = 400000;
constexpr int D = 100;
constexpr int B = 4;
constexpr float NEG_SLOPE = 0.2f;

constexpr int SCAN_CHUNK = 2048;
constexpr int NB_SCAN = (N + SCAN_CHUNK - 1) / SCAN_CHUNK;  // 25
constexpr int CAP = 128;  // per-node LDS edge cache; deg>CAP falls back (Poisson(8): never)

// ---------------- CSR build (counting sort of edges by dst) ----------------

__global__ void k_hist(const int* __restrict__ dst, int* __restrict__ deg) {
  int i = blockIdx.x * blockDim.x + threadIdx.x;
  int stride = gridDim.x * blockDim.x;
  for (; i < E; i += stride) atomicAdd(&deg[dst[i]], 1);
}

__global__ void k_scan1(const int* __restrict__ deg, int* __restrict__ incl,
                        int* __restrict__ bsums) {
  __shared__ int lds[256];
  int tid = threadIdx.x;
  int base = blockIdx.x * SCAN_CHUNK + tid * 8;
  int v[8]; int s = 0;
#pragma unroll
  for (int j = 0; j < 8; ++j) {
    int idx = base + j;
    int x = (idx < N) ? deg[idx] : 0;
    v[j] = x; s += x;
  }
  lds[tid] = s; __syncthreads();
  for (int off = 1; off < 256; off <<= 1) {
    int t = (tid >= off) ? lds[tid - off] : 0;
    __syncthreads();
    lds[tid] += t;
    __syncthreads();
  }
  int run = lds[tid] - s;  // exclusive prefix within block
#pragma unroll
  for (int j = 0; j < 8; ++j) {
    int idx = base + j;
    run += v[j];
    if (idx < N) incl[idx] = run;  // inclusive scan within block
  }
  if (tid == 255) bsums[blockIdx.x] = lds[255];
}

__global__ void k_scan2(int* __restrict__ bsums, int nb) {
  if (threadIdx.x == 0 && blockIdx.x == 0) {
    int run = 0;
    for (int i = 0; i < nb; ++i) { int t = bsums[i]; bsums[i] = run; run += t; }
  }
}

__global__ void k_scan3(const int* __restrict__ incl, const int* __restrict__ bsums,
                        int* __restrict__ offs) {
  int i = blockIdx.x * blockDim.x + threadIdx.x;
  int stride = gridDim.x * blockDim.x;
  for (; i < N; i += stride) {
    offs[i + 1] = incl[i] + bsums[i / SCAN_CHUNK];
    if (i == 0) offs[0] = 0;
  }
}

// scatter edges into CSR order; permute src/etype into position order so
// downstream kernels read contiguous ranges (no indirect per-edge gathers).
__global__ void k_scatter(const int* __restrict__ srcArr, const int* __restrict__ dst,
                          const int* __restrict__ etype, const int* __restrict__ offs,
                          int* __restrict__ cursor, int* __restrict__ ssorted,
                          int* __restrict__ esorted) {
  int i = blockIdx.x * blockDim.x + threadIdx.x;
  int stride = gridDim.x * blockDim.x;
  for (; i < E; i += stride) {
    int d = dst[i];
    int pos = offs[d] + atomicAdd(&cursor[d], 1);
    ssorted[pos] = srcArr[i];
    esorted[pos] = etype[i];
  }
}

// X1[n,:] = emb[entity[n],:]  — hoist the remap so edge gathers are 1-hop.
__global__ void k_gather(const float* __restrict__ emb, const int* __restrict__ entity,
                         float* __restrict__ X) {
  int idx = blockIdx.x * blockDim.x + threadIdx.x;  // float4 index
  int total = N * (D / 4);
  int stride = gridDim.x * blockDim.x;
  for (; idx < total; idx += stride) {
    int n = idx / (D / 4), c = idx % (D / 4);
    int r = entity[n];
    *(float4*)(X + (size_t)n * D + c * 4) = *(const float4*)(emb + (size_t)r * D + c * 4);
  }
}

// ---------------- per-layer kernels ----------------

// qb[b,i] = sum_o basis[b,i,o] * q[o];  kb likewise.
__global__ void k_qbkb(const float* __restrict__ basis, const float* __restrict__ qv,
                       const float* __restrict__ kv, float* __restrict__ qb,
                       float* __restrict__ kb) {
  int t = blockIdx.x * blockDim.x + threadIdx.x;
  if (t < B * D) {
    const float* row = basis + t * D;  // t = b*D+i -> row (b,i,:)
    float sq = 0.f, sk = 0.f;
    for (int o = 0; o < D; ++o) { float r = row[o]; sq += r * qv[o]; sk += r * kv[o]; }
    qb[t] = sq; kb[t] = sk;
  }
}

// xq[n,b] = x[n,:].qb[b,:] ; xk[n,b] = x[n,:].kb[b,:]   — thread per node.
__global__ __launch_bounds__(256) void k_xqxk(
    const float* __restrict__ X, const float* __restrict__ qb,
    const float* __restrict__ kb, float* __restrict__ xq, float* __restrict__ xk) {
  __shared__ float qb_s[B * D], kb_s[B * D];
  int tid = threadIdx.x;
  for (int i = tid; i < B * D; i += 256) { qb_s[i] = qb[i]; kb_s[i] = kb[i]; }
  __syncthreads();
  int n = blockIdx.x * 256 + tid;
  if (n >= N) return;
  const float* x = X + (size_t)n * D;
  float aq[B] = {}, ak[B] = {};
  for (int i = 0; i < D; i += 4) {
    float4 xv = *(const float4*)(x + i);
#pragma unroll
    for (int b = 0; b < B; ++b) {
      float4 qv = *(const float4*)&qb_s[b * D + i];
      float4 kv = *(const float4*)&kb_s[b * D + i];
      aq[b] += xv.x * qv.x + xv.y * qv.y + xv.z * qv.z + xv.w * qv.w;
      ak[b] += xv.x * kv.x + xv.y * kv.y + xv.z * kv.z + xv.w * kv.w;
    }
  }
  *(float4*)(xq + (size_t)n * 4) = make_float4(aq[0], aq[1], aq[2], aq[3]);
  *(float4*)(xk + (size_t)n * 4) = make_float4(ak[0], ak[1], ak[2], ak[3]);
}

__device__ __forceinline__ float edge_score_p(int s, int et,
                                              const float* __restrict__ att,
                                              const float4 xq4,
                                              const float* __restrict__ xk,
                                              float4* a_out) {
  float4 a = *(const float4*)(att + et * 4);
  float4 xs = *(const float4*)(xk + s * 4);
  float qe = a.x * xq4.x + a.y * xq4.y + a.z * xq4.z + a.w * xq4.w;
  float ke = a.x * xs.x + a.y * xs.y + a.z * xs.z + a.w * xs.w;
  float sc = qe + ke;
  *a_out = a;
  return sc >= 0.f ? sc : NEG_SLOPE * sc;
}

// One block (128 thr) per dst node: softmax over its edges + input-space aggregation.
// agg[n,b,:] = sum_edges alpha_e * att[et,b] * x[src,:]
__global__ __launch_bounds__(128) void k_node(
    const float* __restrict__ feat, const int* __restrict__ ssorted,
    const int* __restrict__ esorted, const float* __restrict__ att,
    const float* __restrict__ xq, const float* __restrict__ xk,
    const int* __restrict__ offs, float* __restrict__ agg) {
  int n = blockIdx.x;
  int tid = threadIdx.x;
  int lane = tid & 63, wid = tid >> 6;
  int o0 = offs[n], o1 = offs[n + 1];
  int deg = o1 - o0;
  float4 xq4 = *(const float4*)(xq + (size_t)n * 4);
  __shared__ float red[2];
  __shared__ float sc[CAP];
  __shared__ float4 a4[CAP];
  __shared__ int sbuf[CAP];

  if (deg <= CAP) {
    // compute each edge score ONCE; cache score, att-row, src in LDS
    for (int i = tid; i < deg; i += 128) {
      int s = ssorted[o0 + i];
      int et = esorted[o0 + i];
      float4 a;
      float v = edge_score_p(s, et, att, xq4, xk, &a);
      sc[i] = v; a4[i] = a; sbuf[i] = s;
    }
    __syncthreads();
    // segment max
    float lm = -3.4e38f;
    for (int i = tid; i < deg; i += 128) lm = fmaxf(lm, sc[i]);
#pragma unroll
    for (int off = 32; off >= 1; off >>= 1) lm = fmaxf(lm, __shfl_xor(lm, off));
    if (lane == 0) red[wid] = lm;
    __syncthreads();
    float m = fmaxf(red[0], red[1]);
    __syncthreads();
    // segment sum of exp (stash exp back into sc)
    float ls = 0.f;
    for (int i = tid; i < deg; i += 128) {
      float ex = __expf(sc[i] - m);
      sc[i] = ex;
      ls += ex;
    }
#pragma unroll
    for (int off = 32; off >= 1; off >>= 1) ls += __shfl_xor(ls, off);
    if (lane == 0) red[wid] = ls;
    __syncthreads();
    float inv = 1.f / (red[0] + red[1] + 1e-16f);
    // fold alpha into the att row (each thread owns its own i's — no race)
    for (int i = tid; i < deg; i += 128) {
      float p = sc[i] * inv;
      float4 a = a4[i];
      a.x *= p; a.y *= p; a.z *= p; a.w *= p;
      a4[i] = a;
    }
    __syncthreads();
    // aggregate x[src] with per-basis coefficients (threads = feature dim)
    if (tid < D) {
      float acc0 = 0.f, acc1 = 0.f, acc2 = 0.f, acc3 = 0.f;
      int i = 0;
      for (; i + 1 < deg; i += 2) {  // 2 gathers in flight
        float4 aA = a4[i];     int sA = sbuf[i];
        float4 aB = a4[i + 1]; int sB = sbuf[i + 1];
        float xA = feat[(size_t)sA * D + tid];
        float xB = feat[(size_t)sB * D + tid];
        acc0 += aA.x * xA + aB.x * xB;
        acc1 += aA.y * xA + aB.y * xB;
        acc2 += aA.z * xA + aB.z * xB;
        acc3 += aA.w * xA + aB.w * xB;
      }
      if (i < deg) {
        float4 a = a4[i]; int s = sbuf[i];
        float xv = feat[(size_t)s * D + tid];
        acc0 += a.x * xv; acc1 += a.y * xv; acc2 += a.z * xv; acc3 += a.w * xv;
      }
      float* ag = agg + (size_t)n * (B * D) + tid;
      ag[0 * D] = acc0; ag[1 * D] = acc1; ag[2 * D] = acc2; ag[3 * D] = acc3;
    }
  } else {
    // fallback: recompute path (correct for any deg)
    float lm = -3.4e38f;
    for (int i = tid; i < deg; i += 128) {
      float4 a;
      lm = fmaxf(lm, edge_score_p(ssorted[o0 + i], esorted[o0 + i], att, xq4, xk, &a));
    }
#pragma unroll
    for (int off = 32; off >= 1; off >>= 1) lm = fmaxf(lm, __shfl_xor(lm, off));
    if (lane == 0) red[wid] = lm;
    __syncthreads();
    float m = fmaxf(red[0], red[1]);
    __syncthreads();
    float ls = 0.f;
    for (int i = tid; i < deg; i += 128) {
      float4 a;
      ls += __expf(edge_score_p(ssorted[o0 + i], esorted[o0 + i], att, xq4, xk, &a) - m);
    }
#pragma unroll
    for (int off = 32; off >= 1; off >>= 1) ls += __shfl_xor(ls, off);
    if (lane == 0) red[wid] = ls;
    __syncthreads();
    float inv = 1.f / (red[0] + red[1] + 1e-16f);
    if (tid < D) {
      float acc0 = 0.f, acc1 = 0.f, acc2 = 0.f, acc3 = 0.f;
      for (int i = 0; i < deg; ++i) {
        int s = ssorted[o0 + i];
        float4 a;
        float v = edge_score_p(s, esorted[o0 + i], att, xq4, xk, &a);
        float p = __expf(v - m) * inv;
        float xv = feat[(size_t)s * D + tid];
        acc0 += p * a.x * xv;
        acc1 += p * a.y * xv;
        acc2 += p * a.z * xv;
        acc3 += p * a.w * xv;
      }
      float* ag = agg + (size_t)n * (B * D) + tid;
      ag[0 * D] = acc0; ag[1 * D] = acc1; ag[2 * D] = acc2; ag[3 * D] = acc3;
    }
  }
}

// out[n,o] = sum_k A[n,k] * W[k,o] + bias[o]   (W = basis viewed [400,100]), opt ReLU
// BN=128 nodes, BO=128 (100 padded), BK=32. 256 thr: 16 o-threads x 16 n-threads,
// 8x8 register block -> 64 FMA per 4 ds_read_b128 (A reads 16-way broadcast,
// W reads 4-way broadcast: both conflict-free).
template <bool RELU>
__global__ __launch_bounds__(256) void k_gemm(const float* __restrict__ A,
                                              const float* __restrict__ W,
                                              const float* __restrict__ bias,
                                              float* __restrict__ out) {
  __shared__ float A_lds[32][132];  // [k][n], pad 132 keeps 16B alignment per row
  __shared__ float W_lds[32][128];  // [k][o], o padded with zeros
  int tid = threadIdx.x;
  int nblk = blockIdx.x * 128;
  int o_base = (tid & 15) * 8;
  int n_base = (tid >> 4) * 8;
  float acc[8][8] = {};
  for (int kc = 0; kc < 400; kc += 32) {
    // stage A: 128 rows x 32 k = 1024 float4, 8 lanes per row (coalesced 128B/row)
#pragma unroll
    for (int j = 0; j < 4; ++j) {
      int idx = tid + j * 256;
      int n_l = idx >> 3;
      int k4 = (idx & 7) * 4;
      float4 av = make_float4(0.f, 0.f, 0.f, 0.f);
      int gn = nblk + n_l;
      if (gn < N && kc + k4 < 400) av = *(const float4*)(A + (size_t)gn * 400 + kc + k4);
      A_lds[k4 + 0][n_l] = av.x;
      A_lds[k4 + 1][n_l] = av.y;
      A_lds[k4 + 2][n_l] = av.z;
      A_lds[k4 + 3][n_l] = av.w;
    }
    // stage W: 32 k x 128 o slots = 1024 float4
#pragma unroll
    for (int j = 0; j < 4; ++j) {
      int idx = tid + j * 256;
      int k = idx >> 5;
      int o4 = (idx & 31) * 4;
      float4 v = make_float4(0.f, 0.f, 0.f, 0.f);
      if (o4 < D && kc + k < 400) v = *(const float4*)(W + (size_t)(kc + k) * D + o4);
      *(float4*)&W_lds[k][o4] = v;
    }
    __syncthreads();
#pragma unroll 4
    for (int k = 0; k < 32; ++k) {
      float4 w0 = *(const float4*)&W_lds[k][o_base];
      float4 w1 = *(const float4*)&W_lds[k][o_base + 4];
      float4 a0 = *(const float4*)&A_lds[k][n_base];
      float4 a1 = *(const float4*)&A_lds[k][n_base + 4];
      float a[8] = {a0.x, a0.y, a0.z, a0.w, a1.x, a1.y, a1.z, a1.w};
      float w[8] = {w0.x, w0.y, w0.z, w0.w, w1.x, w1.y, w1.z, w1.w};
#pragma unroll
      for (int i = 0; i < 8; ++i)
#pragma unroll
        for (int jj = 0; jj < 8; ++jj) acc[i][jj] += a[i] * w[jj];
    }
    __syncthreads();
  }
  if (o_base < D) {
    bool hi_ok = (o_base + 7 < D);
    float4 b0 = *(const float4*)(bias + o_base);
    float4 b1 = hi_ok ? *(const float4*)(bias + o_base + 4) : make_float4(0, 0, 0, 0);
#pragma unroll
    for (int i = 0; i < 8; ++i) {
      int gn = nblk + n_base + i;
      if (gn < N) {
        float4 r0, r1;
        r0.x = acc[i][0] + b0.x; r0.y = acc[i][1] + b0.y;
        r0.z = acc[i][2] + b0.z; r0.w = acc[i][3] + b0.w;
        r1.x = acc[i][4] + b1.x; r1.y = acc[i][5] + b1.y;
        r1.z = acc[i][6] + b1.z; r1.w = acc[i][7] + b1.w;
        if (RELU) {
          r0.x = fmaxf(r0.x, 0.f); r0.y = fmaxf(r0.y, 0.f);
          r0.z = fmaxf(r0.z, 0.f); r0.w = fmaxf(r0.w, 0.f);
          r1.x = fmaxf(r1.x, 0.f); r1.y = fmaxf(r1.y, 0.f);
          r1.z = fmaxf(r1.z, 0.f); r1.w = fmaxf(r1.w, 0.f);
        }
        *(float4*)(out + (size_t)gn * D + o_base) = r0;
        if (hi_ok) *(float4*)(out + (size_t)gn * D + o_base + 4) = r1;
      }
    }
  }
}

// ---------------- launch ----------------

extern "C" void kernel_launch(void* const* d_in, const int* in_sizes, int n_in,
                              void* d_out, int out_size, void* d_ws, size_t ws_size,
                              hipStream_t stream) {
  const int* entity = (const int*)d_in[0];
  const int* edge_index = (const int*)d_in[1];
  const int* etype = (const int*)d_in[2];
  // d_in[3] = edge_norm: unused by the reference
  const float* emb = (const float*)d_in[4];
  const float* basis1 = (const float*)d_in[5];
  const float* att1 = (const float*)d_in[6];
  const float* q1 = (const float*)d_in[7];
  const float* k1 = (const float*)d_in[8];
  const float* bias1 = (const float*)d_in[9];
  const float* basis2 = (const float*)d_in[10];
  const float* att2 = (const float*)d_in[11];
  const float* q2 = (const float*)d_in[12];
  const float* k2 = (const float*)d_in[13];
  const float* bias2 = (const float*)d_in[14];
  float* out = (float*)d_out;

  const int* srcArr = edge_index;       // edge_index[0,:]
  const int* dstArr = edge_index + E;   // edge_index[1,:]

  // workspace layout (~106 MB)
  float* ws = (float*)d_ws;
  float* agg = ws;                               // N*B*D = 20,000,000 floats
  float* X1 = agg + (size_t)N * B * D;           // N*D = 5,000,000
  float* xq = X1 + (size_t)N * D;                // N*B
  float* xk = xq + (size_t)N * B;                // N*B
  float* qb = xk + (size_t)N * B;                // B*D
  float* kb = qb + B * D;                        // B*D
  int* ssorted = (int*)(kb + B * D);             // E
  int* esorted = ssorted + E;                    // E
  int* offs = esorted + E;                       // N+1
  int* deg = offs + (N + 1);                     // N
  int* cursor = deg + N;                         // N
  int* incl = cursor + N;                        // N
  int* bsums = incl + N;                         // NB_SCAN

  hipMemsetAsync(deg, 0, N * sizeof(int), stream);
  hipMemsetAsync(cursor, 0, N * sizeof(int), stream);
  k_hist<<<512, 256, 0, stream>>>(dstArr, deg);
  k_scan1<<<NB_SCAN, 256, 0, stream>>>(deg, incl, bsums);
  k_scan2<<<1, 64, 0, stream>>>(bsums, NB_SCAN);
  k_scan3<<<256, 256, 0, stream>>>(incl, bsums, offs);
  k_scatter<<<512, 256, 0, stream>>>(srcArr, dstArr, etype, offs, cursor, ssorted, esorted);
  k_gather<<<1024, 256, 0, stream>>>(emb, entity, X1);

  // ---- layer 1: x = X1, ReLU; x1 stored in d_out ----
  k_qbkb<<<2, 256, 0, stream>>>(basis1, q1, k1, qb, kb);
  k_xqxk<<<(N + 255) / 256, 256, 0, stream>>>(X1, qb, kb, xq, xk);
  k_node<<<N, 128, 0, stream>>>(X1, ssorted, esorted, att1, xq, xk, offs, agg);
  k_gemm<true><<<(N + 127) / 128, 256, 0, stream>>>(agg, basis1, bias1, out);

  // ---- layer 2: x = x1 (in d_out), no ReLU ----
  k_qbkb<<<2, 256, 0, stream>>>(basis2, q2, k2, qb, kb);
  k_xqxk<<<(N + 255) / 256, 256, 0, stream>>>(out, qb, kb, xq, xk);
  k_node<<<N, 128, 0, stream>>>(out, ssorted, esorted, att2, xq, xk, offs, agg);
  k_gemm<false><<<(N + 127) / 128, 256, 0, stream>>>(agg, basis2, bias2, out);
}

// Round 5
// 484.605 us; speedup vs baseline: 1.3385x; 1.0455x over previous
//
#include <hip/hip_runtime.h>

constexpr int N = 50000;
constexpr int E = 400000;
constexpr int D = 100;
constexpr int B = 4;
constexpr float NEG_SLOPE = 0.2f;

constexpr int SCAN_CHUNK = 2048;
constexpr int NB_SCAN = (N + SCAN_CHUNK - 1) / SCAN_CHUNK;  // 25
constexpr int CAP = 128;  // per-node LDS edge cache; deg>CAP falls back (Poisson(8): never)

// ---------------- CSR build (counting sort of edges by dst) ----------------

__global__ void k_hist(const int* __restrict__ dst, int* __restrict__ deg) {
  int i = blockIdx.x * blockDim.x + threadIdx.x;
  int stride = gridDim.x * blockDim.x;
  for (; i < E; i += stride) atomicAdd(&deg[dst[i]], 1);
}

__global__ void k_scan1(const int* __restrict__ deg, int* __restrict__ incl,
                        int* __restrict__ bsums) {
  __shared__ int lds[256];
  int tid = threadIdx.x;
  int base = blockIdx.x * SCAN_CHUNK + tid * 8;
  int v[8]; int s = 0;
#pragma unroll
  for (int j = 0; j < 8; ++j) {
    int idx = base + j;
    int x = (idx < N) ? deg[idx] : 0;
    v[j] = x; s += x;
  }
  lds[tid] = s; __syncthreads();
  for (int off = 1; off < 256; off <<= 1) {
    int t = (tid >= off) ? lds[tid - off] : 0;
    __syncthreads();
    lds[tid] += t;
    __syncthreads();
  }
  int run = lds[tid] - s;  // exclusive prefix within block
#pragma unroll
  for (int j = 0; j < 8; ++j) {
    int idx = base + j;
    run += v[j];
    if (idx < N) incl[idx] = run;  // inclusive scan within block
  }
  if (tid == 255) bsums[blockIdx.x] = lds[255];
}

__global__ void k_scan2(int* __restrict__ bsums, int nb) {
  if (threadIdx.x == 0 && blockIdx.x == 0) {
    int run = 0;
    for (int i = 0; i < nb; ++i) { int t = bsums[i]; bsums[i] = run; run += t; }
  }
}

__global__ void k_scan3(const int* __restrict__ incl, const int* __restrict__ bsums,
                        int* __restrict__ offs) {
  int i = blockIdx.x * blockDim.x + threadIdx.x;
  int stride = gridDim.x * blockDim.x;
  for (; i < N; i += stride) {
    offs[i + 1] = incl[i] + bsums[i / SCAN_CHUNK];
    if (i == 0) offs[0] = 0;
  }
}

// scatter edges into CSR order; permute src/etype into position order so
// downstream kernels read contiguous ranges (no indirect per-edge gathers).
__global__ void k_scatter(const int* __restrict__ srcArr, const int* __restrict__ dst,
                          const int* __restrict__ etype, const int* __restrict__ offs,
                          int* __restrict__ cursor, int* __restrict__ ssorted,
                          int* __restrict__ esorted) {
  int i = blockIdx.x * blockDim.x + threadIdx.x;
  int stride = gridDim.x * blockDim.x;
  for (; i < E; i += stride) {
    int d = dst[i];
    int pos = offs[d] + atomicAdd(&cursor[d], 1);
    ssorted[pos] = srcArr[i];
    esorted[pos] = etype[i];
  }
}

// X1[n,:] = emb[entity[n],:]  — hoist the remap so edge gathers are 1-hop.
__global__ void k_gather(const float* __restrict__ emb, const int* __restrict__ entity,
                         float* __restrict__ X) {
  int idx = blockIdx.x * blockDim.x + threadIdx.x;  // float4 index
  int total = N * (D / 4);
  int stride = gridDim.x * blockDim.x;
  for (; idx < total; idx += stride) {
    int n = idx / (D / 4), c = idx % (D / 4);
    int r = entity[n];
    *(float4*)(X + (size_t)n * D + c * 4) = *(const float4*)(emb + (size_t)r * D + c * 4);
  }
}

// ---------------- per-layer kernels ----------------

// qb[b,i] = sum_o basis[b,i,o] * q[o];  kb likewise.
__global__ void k_qbkb(const float* __restrict__ basis, const float* __restrict__ qv,
                       const float* __restrict__ kv, float* __restrict__ qb,
                       float* __restrict__ kb) {
  int t = blockIdx.x * blockDim.x + threadIdx.x;
  if (t < B * D) {
    const float* row = basis + t * D;  // t = b*D+i -> row (b,i,:)
    float sq = 0.f, sk = 0.f;
    for (int o = 0; o < D; ++o) { float r = row[o]; sq += r * qv[o]; sk += r * kv[o]; }
    qb[t] = sq; kb[t] = sk;
  }
}

// xq[n,b] = x[n,:].qb[b,:] ; xk[n,b] = x[n,:].kb[b,:]   — thread per node.
__global__ __launch_bounds__(256) void k_xqxk(
    const float* __restrict__ X, const float* __restrict__ qb,
    const float* __restrict__ kb, float* __restrict__ xq, float* __restrict__ xk) {
  __shared__ float qb_s[B * D], kb_s[B * D];
  int tid = threadIdx.x;
  for (int i = tid; i < B * D; i += 256) { qb_s[i] = qb[i]; kb_s[i] = kb[i]; }
  __syncthreads();
  int n = blockIdx.x * 256 + tid;
  if (n >= N) return;
  const float* x = X + (size_t)n * D;
  float aq[B] = {}, ak[B] = {};
  for (int i = 0; i < D; i += 4) {
    float4 xv = *(const float4*)(x + i);
#pragma unroll
    for (int b = 0; b < B; ++b) {
      float4 qv = *(const float4*)&qb_s[b * D + i];
      float4 kv = *(const float4*)&kb_s[b * D + i];
      aq[b] += xv.x * qv.x + xv.y * qv.y + xv.z * qv.z + xv.w * qv.w;
      ak[b] += xv.x * kv.x + xv.y * kv.y + xv.z * kv.z + xv.w * kv.w;
    }
  }
  *(float4*)(xq + (size_t)n * 4) = make_float4(aq[0], aq[1], aq[2], aq[3]);
  *(float4*)(xk + (size_t)n * 4) = make_float4(ak[0], ak[1], ak[2], ak[3]);
}

__device__ __forceinline__ float edge_score_p(int s, int et,
                                              const float* __restrict__ att,
                                              const float4 xq4,
                                              const float* __restrict__ xk,
                                              float4* a_out) {
  float4 a = *(const float4*)(att + et * 4);
  float4 xs = *(const float4*)(xk + s * 4);
  float qe = a.x * xq4.x + a.y * xq4.y + a.z * xq4.z + a.w * xq4.w;
  float ke = a.x * xs.x + a.y * xs.y + a.z * xs.z + a.w * xs.w;
  float sc = qe + ke;
  *a_out = a;
  return sc >= 0.f ? sc : NEG_SLOPE * sc;
}

// One block (128 thr) per dst node: softmax over its edges + input-space aggregation.
// agg[n,b,:] = sum_edges alpha_e * att[et,b] * x[src,:]
__global__ __launch_bounds__(128) void k_node(
    const float* __restrict__ feat, const int* __restrict__ ssorted,
    const int* __restrict__ esorted, const float* __restrict__ att,
    const float* __restrict__ xq, const float* __restrict__ xk,
    const int* __restrict__ offs, float* __restrict__ agg) {
  int n = blockIdx.x;
  int tid = threadIdx.x;
  int lane = tid & 63, wid = tid >> 6;
  int o0 = offs[n], o1 = offs[n + 1];
  int deg = o1 - o0;
  float4 xq4 = *(const float4*)(xq + (size_t)n * 4);
  __shared__ float red[2];
  __shared__ float sc[CAP];
  __shared__ float4 a4[CAP];
  __shared__ int sbuf[CAP];

  if (deg <= CAP) {
    // compute each edge score ONCE; cache score, att-row, src in LDS
    for (int i = tid; i < deg; i += 128) {
      int s = ssorted[o0 + i];
      int et = esorted[o0 + i];
      float4 a;
      float v = edge_score_p(s, et, att, xq4, xk, &a);
      sc[i] = v; a4[i] = a; sbuf[i] = s;
    }
    __syncthreads();
    // segment max
    float lm = -3.4e38f;
    for (int i = tid; i < deg; i += 128) lm = fmaxf(lm, sc[i]);
#pragma unroll
    for (int off = 32; off >= 1; off >>= 1) lm = fmaxf(lm, __shfl_xor(lm, off));
    if (lane == 0) red[wid] = lm;
    __syncthreads();
    float m = fmaxf(red[0], red[1]);
    __syncthreads();
    // segment sum of exp (stash exp back into sc)
    float ls = 0.f;
    for (int i = tid; i < deg; i += 128) {
      float ex = __expf(sc[i] - m);
      sc[i] = ex;
      ls += ex;
    }
#pragma unroll
    for (int off = 32; off >= 1; off >>= 1) ls += __shfl_xor(ls, off);
    if (lane == 0) red[wid] = ls;
    __syncthreads();
    float inv = 1.f / (red[0] + red[1] + 1e-16f);
    // fold alpha into the att row (each thread owns its own i's — no race)
    for (int i = tid; i < deg; i += 128) {
      float p = sc[i] * inv;
      float4 a = a4[i];
      a.x *= p; a.y *= p; a.z *= p; a.w *= p;
      a4[i] = a;
    }
    __syncthreads();
    // aggregate x[src] with per-basis coefficients (threads = feature dim)
    if (tid < D) {
      float acc0 = 0.f, acc1 = 0.f, acc2 = 0.f, acc3 = 0.f;
      int i = 0;
      for (; i + 1 < deg; i += 2) {  // 2 gathers in flight
        float4 aA = a4[i];     int sA = sbuf[i];
        float4 aB = a4[i + 1]; int sB = sbuf[i + 1];
        float xA = feat[(size_t)sA * D + tid];
        float xB = feat[(size_t)sB * D + tid];
        acc0 += aA.x * xA + aB.x * xB;
        acc1 += aA.y * xA + aB.y * xB;
        acc2 += aA.z * xA + aB.z * xB;
        acc3 += aA.w * xA + aB.w * xB;
      }
      if (i < deg) {
        float4 a = a4[i]; int s = sbuf[i];
        float xv = feat[(size_t)s * D + tid];
        acc0 += a.x * xv; acc1 += a.y * xv; acc2 += a.z * xv; acc3 += a.w * xv;
      }
      float* ag = agg + (size_t)n * (B * D) + tid;
      ag[0 * D] = acc0; ag[1 * D] = acc1; ag[2 * D] = acc2; ag[3 * D] = acc3;
    }
  } else {
    // fallback: recompute path (correct for any deg)
    float lm = -3.4e38f;
    for (int i = tid; i < deg; i += 128) {
      float4 a;
      lm = fmaxf(lm, edge_score_p(ssorted[o0 + i], esorted[o0 + i], att, xq4, xk, &a));
    }
#pragma unroll
    for (int off = 32; off >= 1; off >>= 1) lm = fmaxf(lm, __shfl_xor(lm, off));
    if (lane == 0) red[wid] = lm;
    __syncthreads();
    float m = fmaxf(red[0], red[1]);
    __syncthreads();
    float ls = 0.f;
    for (int i = tid; i < deg; i += 128) {
      float4 a;
      ls += __expf(edge_score_p(ssorted[o0 + i], esorted[o0 + i], att, xq4, xk, &a) - m);
    }
#pragma unroll
    for (int off = 32; off >= 1; off >>= 1) ls += __shfl_xor(ls, off);
    if (lane == 0) red[wid] = ls;
    __syncthreads();
    float inv = 1.f / (red[0] + red[1] + 1e-16f);
    if (tid < D) {
      float acc0 = 0.f, acc1 = 0.f, acc2 = 0.f, acc3 = 0.f;
      for (int i = 0; i < deg; ++i) {
        int s = ssorted[o0 + i];
        float4 a;
        float v = edge_score_p(s, esorted[o0 + i], att, xq4, xk, &a);
        float p = __expf(v - m) * inv;
        float xv = feat[(size_t)s * D + tid];
        acc0 += p * a.x * xv;
        acc1 += p * a.y * xv;
        acc2 += p * a.z * xv;
        acc3 += p * a.w * xv;
      }
      float* ag = agg + (size_t)n * (B * D) + tid;
      ag[0 * D] = acc0; ag[1 * D] = acc1; ag[2 * D] = acc2; ag[3 * D] = acc3;
    }
  }
}

// out[n,o] = sum_k A[n,k] * W[k,o] + bias[o]   (W = basis viewed [400,100]), opt ReLU
// BN=64, BO=128(100 padded), BK=32; 256 thr = 16 o-thr x 16 n-thr, each 4n x 8o.
// The 8 o's per thread are split as {o_lo..o_lo+3, o_lo+64..o_lo+67} so a wave's
// 16 o-threads read 64 contiguous LDS words per float4 -> 2-way bank alias (free).
// A is stored TRANSPOSED [n][k] with 36-word rows: staging = contiguous float4
// writes (conflict-free), reads = 16-lane broadcast, 2-way alias worst case.
template <bool RELU>
__global__ __launch_bounds__(256) void k_gemm(const float* __restrict__ A,
                                              const float* __restrict__ W,
                                              const float* __restrict__ bias,
                                              float* __restrict__ out) {
  __shared__ float A_lds[64][36];   // [n][k], 36*4B row (16B-aligned, odd bank group)
  __shared__ float W_lds[32][128];  // [k][o], o padded with zeros
  int tid = threadIdx.x;
  int nblk = blockIdx.x * 64;
  int o_lo = (tid & 15) * 4;
  int n_base = (tid >> 4) * 4;
  float acc[4][8] = {};
  for (int kc = 0; kc < 400; kc += 32) {
    // stage A: 64 rows x 8 k-quads = 512 float4, 2 per thread, contiguous writes
#pragma unroll
    for (int j = 0; j < 2; ++j) {
      int idx = tid + j * 256;
      int n_l = idx >> 3;
      int k4 = (idx & 7) * 4;
      int gn = nblk + n_l;
      float4 av = make_float4(0.f, 0.f, 0.f, 0.f);
      if (gn < N && kc + k4 + 3 < 400) av = *(const float4*)(A + (size_t)gn * 400 + kc + k4);
      *(float4*)&A_lds[n_l][k4] = av;
    }
    // stage W: 32 k x 32 o-quads = 1024 float4, 4 per thread, contiguous writes
#pragma unroll
    for (int j = 0; j < 4; ++j) {
      int idx = tid + j * 256;
      int k = idx >> 5;
      int o4 = (idx & 31) * 4;
      float4 v = make_float4(0.f, 0.f, 0.f, 0.f);
      if (o4 < D && kc + k < 400) v = *(const float4*)(W + (size_t)(kc + k) * D + o4);
      *(float4*)&W_lds[k][o4] = v;
    }
    __syncthreads();
#pragma unroll 4
    for (int k = 0; k < 32; ++k) {
      float4 w0 = *(const float4*)&W_lds[k][o_lo];
      float4 w1 = *(const float4*)&W_lds[k][o_lo + 64];
      float w[8] = {w0.x, w0.y, w0.z, w0.w, w1.x, w1.y, w1.z, w1.w};
#pragma unroll
      for (int i = 0; i < 4; ++i) {
        float a = A_lds[n_base + i][k];
#pragma unroll
        for (int jj = 0; jj < 8; ++jj) acc[i][jj] += a * w[jj];
      }
    }
    __syncthreads();
  }
  // epilogue: o coverage = {0..63} via o_lo, {64..99} via o_lo+64 (o_lo<=32)
  bool hi_ok = (o_lo + 64 < D - 3);  // o_lo+67 <= 99
  float4 b0 = *(const float4*)(bias + o_lo);
  float4 b1 = hi_ok ? *(const float4*)(bias + o_lo + 64) : make_float4(0, 0, 0, 0);
#pragma unroll
  for (int i = 0; i < 4; ++i) {
    int gn = nblk + n_base + i;
    if (gn < N) {
      float4 r0, r1;
      r0.x = acc[i][0] + b0.x; r0.y = acc[i][1] + b0.y;
      r0.z = acc[i][2] + b0.z; r0.w = acc[i][3] + b0.w;
      r1.x = acc[i][4] + b1.x; r1.y = acc[i][5] + b1.y;
      r1.z = acc[i][6] + b1.z; r1.w = acc[i][7] + b1.w;
      if (RELU) {
        r0.x = fmaxf(r0.x, 0.f); r0.y = fmaxf(r0.y, 0.f);
        r0.z = fmaxf(r0.z, 0.f); r0.w = fmaxf(r0.w, 0.f);
        r1.x = fmaxf(r1.x, 0.f); r1.y = fmaxf(r1.y, 0.f);
        r1.z = fmaxf(r1.z, 0.f); r1.w = fmaxf(r1.w, 0.f);
      }
      *(float4*)(out + (size_t)gn * D + o_lo) = r0;
      if (hi_ok) *(float4*)(out + (size_t)gn * D + o_lo + 64) = r1;
    }
  }
}

// ---------------- launch ----------------

extern "C" void kernel_launch(void* const* d_in, const int* in_sizes, int n_in,
                              void* d_out, int out_size, void* d_ws, size_t ws_size,
                              hipStream_t stream) {
  const int* entity = (const int*)d_in[0];
  const int* edge_index = (const int*)d_in[1];
  const int* etype = (const int*)d_in[2];
  // d_in[3] = edge_norm: unused by the reference
  const float* emb = (const float*)d_in[4];
  const float* basis1 = (const float*)d_in[5];
  const float* att1 = (const float*)d_in[6];
  const float* q1 = (const float*)d_in[7];
  const float* k1 = (const float*)d_in[8];
  const float* bias1 = (const float*)d_in[9];
  const float* basis2 = (const float*)d_in[10];
  const float* att2 = (const float*)d_in[11];
  const float* q2 = (const float*)d_in[12];
  const float* k2 = (const float*)d_in[13];
  const float* bias2 = (const float*)d_in[14];
  float* out = (float*)d_out;

  const int* srcArr = edge_index;       // edge_index[0,:]
  const int* dstArr = edge_index + E;   // edge_index[1,:]

  // workspace layout (~106 MB)
  float* ws = (float*)d_ws;
  float* agg = ws;                               // N*B*D = 20,000,000 floats
  float* X1 = agg + (size_t)N * B * D;           // N*D = 5,000,000
  float* xq = X1 + (size_t)N * D;                // N*B
  float* xk = xq + (size_t)N * B;                // N*B
  float* qb = xk + (size_t)N * B;                // B*D
  float* kb = qb + B * D;                        // B*D
  int* ssorted = (int*)(kb + B * D);             // E
  int* esorted = ssorted + E;                    // E
  int* offs = esorted + E;                       // N+1
  int* deg = offs + (N + 1);                     // N
  int* cursor = deg + N;                         // N
  int* incl = cursor + N;                        // N
  int* bsums = incl + N;                         // NB_SCAN

  hipMemsetAsync(deg, 0, N * sizeof(int), stream);
  hipMemsetAsync(cursor, 0, N * sizeof(int), stream);
  k_hist<<<512, 256, 0, stream>>>(dstArr, deg);
  k_scan1<<<NB_SCAN, 256, 0, stream>>>(deg, incl, bsums);
  k_scan2<<<1, 64, 0, stream>>>(bsums, NB_SCAN);
  k_scan3<<<256, 256, 0, stream>>>(incl, bsums, offs);
  k_scatter<<<512, 256, 0, stream>>>(srcArr, dstArr, etype, offs, cursor, ssorted, esorted);
  k_gather<<<1024, 256, 0, stream>>>(emb, entity, X1);

  // ---- layer 1: x = X1, ReLU; x1 stored in d_out ----
  k_qbkb<<<2, 256, 0, stream>>>(basis1, q1, k1, qb, kb);
  k_xqxk<<<(N + 255) / 256, 256, 0, stream>>>(X1, qb, kb, xq, xk);
  k_node<<<N, 128, 0, stream>>>(X1, ssorted, esorted, att1, xq, xk, offs, agg);
  k_gemm<true><<<(N + 63) / 64, 256, 0, stream>>>(agg, basis1, bias1, out);

  // ---- layer 2: x = x1 (in d_out), no ReLU ----
  k_qbkb<<<2, 256, 0, stream>>>(basis2, q2, k2, qb, kb);
  k_xqxk<<<(N + 255) / 256, 256, 0, stream>>>(out, qb, kb, xq, xk);
  k_node<<<N, 128, 0, stream>>>(out, ssorted, esorted, att2, xq, xk, offs, agg);
  k_gemm<false><<<(N + 63) / 64, 256, 0, stream>>>(agg, basis2, bias2, out);
}